// Round 2
// baseline (168.692 us; speedup 1.0000x reference)
//
#include <hip/hip_runtime.h>
#include <math.h>

#define BLOCK 256
#define GRID 2048
#define RELEASE_PROB 0.9f

// Fused single-kernel reduction:
//   - grid-stride float4 accumulate (unroll x2 -> 8 loads in flight)
//   - per-block reduce -> partials[bid] (device-scope atomic store)
//   - atomic ticket; last block re-reduces all partials, applies
//     threshold + tanh, writes the scalar output.
// Deterministic: partials are per-block deterministic, final reduce order is
// fixed; which block happens to be last does not affect the value.
__global__ __launch_bounds__(BLOCK) void neuron_fused(
    const float4* __restrict__ x,
    const float4* __restrict__ w,
    const float4* __restrict__ f,
    const float4* __restrict__ u,
    const float* __restrict__ threshold,
    float* __restrict__ out,
    float* __restrict__ partials,
    unsigned int* __restrict__ counter,
    int n4)
{
    const int tid = blockIdx.x * BLOCK + threadIdx.x;
    const int stride = GRID * BLOCK;

    float acc = 0.0f;
    int i = tid;
    // main loop, unrolled x2 (n4 = 4M, stride = 512K -> exactly 4 iters here,
    // but written generally with a tail loop)
    for (; i + stride < n4; i += 2 * stride) {
        const int j = i + stride;
        const float4 xv0 = x[i], wv0 = w[i], fv0 = f[i], uv0 = u[i];
        const float4 xv1 = x[j], wv1 = w[j], fv1 = f[j], uv1 = u[j];
        acc += (uv0.x < RELEASE_PROB) ? wv0.x * fv0.x * xv0.x : 0.0f;
        acc += (uv0.y < RELEASE_PROB) ? wv0.y * fv0.y * xv0.y : 0.0f;
        acc += (uv0.z < RELEASE_PROB) ? wv0.z * fv0.z * xv0.z : 0.0f;
        acc += (uv0.w < RELEASE_PROB) ? wv0.w * fv0.w * xv0.w : 0.0f;
        acc += (uv1.x < RELEASE_PROB) ? wv1.x * fv1.x * xv1.x : 0.0f;
        acc += (uv1.y < RELEASE_PROB) ? wv1.y * fv1.y * xv1.y : 0.0f;
        acc += (uv1.z < RELEASE_PROB) ? wv1.z * fv1.z * xv1.z : 0.0f;
        acc += (uv1.w < RELEASE_PROB) ? wv1.w * fv1.w * xv1.w : 0.0f;
    }
    for (; i < n4; i += stride) {
        const float4 xv = x[i], wv = w[i], fv = f[i], uv = u[i];
        acc += (uv.x < RELEASE_PROB) ? wv.x * fv.x * xv.x : 0.0f;
        acc += (uv.y < RELEASE_PROB) ? wv.y * fv.y * xv.y : 0.0f;
        acc += (uv.z < RELEASE_PROB) ? wv.z * fv.z * xv.z : 0.0f;
        acc += (uv.w < RELEASE_PROB) ? wv.w * fv.w * xv.w : 0.0f;
    }

    // wave64 butterfly reduce
    #pragma unroll
    for (int off = 32; off > 0; off >>= 1)
        acc += __shfl_down(acc, off, 64);

    __shared__ float sm[BLOCK / 64];
    __shared__ int is_last;
    const int lane = threadIdx.x & 63;
    const int wave = threadIdx.x >> 6;
    if (lane == 0) sm[wave] = acc;
    __syncthreads();

    if (threadIdx.x == 0) {
        float s = 0.0f;
        #pragma unroll
        for (int k = 0; k < BLOCK / 64; ++k) s += sm[k];
        // device-scope (agent) store so the last block sees it across XCDs
        __hip_atomic_store(&partials[blockIdx.x], s,
                           __ATOMIC_RELEASE, __HIP_MEMORY_SCOPE_AGENT);
        const unsigned int t = __hip_atomic_fetch_add(
            counter, 1u, __ATOMIC_ACQ_REL, __HIP_MEMORY_SCOPE_AGENT);
        is_last = (t == GRID - 1) ? 1 : 0;
    }
    __syncthreads();

    if (is_last) {
        float acc2 = 0.0f;
        for (int k = threadIdx.x; k < GRID; k += BLOCK)
            acc2 += __hip_atomic_load(&partials[k],
                                      __ATOMIC_RELAXED, __HIP_MEMORY_SCOPE_AGENT);
        #pragma unroll
        for (int off = 32; off > 0; off >>= 1)
            acc2 += __shfl_down(acc2, off, 64);
        if (lane == 0) sm[wave] = acc2;
        __syncthreads();
        if (threadIdx.x == 0) {
            float total = 0.0f;
            #pragma unroll
            for (int k = 0; k < BLOCK / 64; ++k) total += sm[k];
            out[0] = (total > threshold[0]) ? tanhf(total) : 0.0f;
        }
    }
}

extern "C" void kernel_launch(void* const* d_in, const int* in_sizes, int n_in,
                              void* d_out, int out_size, void* d_ws, size_t ws_size,
                              hipStream_t stream)
{
    const float* x   = (const float*)d_in[0];
    const float* w   = (const float*)d_in[1];
    const float* f   = (const float*)d_in[2];
    const float* u   = (const float*)d_in[3];
    const float* thr = (const float*)d_in[4];

    float* out = (float*)d_out;
    float* partials = (float*)d_ws;                          // GRID floats
    unsigned int* counter = (unsigned int*)((char*)d_ws + GRID * sizeof(float));

    const int n  = in_sizes[0];   // 16777216
    const int n4 = n / 4;

    // counter must be zero at kernel start on EVERY call (ws is poisoned once,
    // and the kernel leaves counter == GRID behind).
    hipMemsetAsync(counter, 0, sizeof(unsigned int), stream);

    neuron_fused<<<GRID, BLOCK, 0, stream>>>(
        (const float4*)x, (const float4*)w, (const float4*)f, (const float4*)u,
        thr, out, partials, counter, n4);
}

// Round 3
// 45.575 us; speedup vs baseline: 3.7014x; 3.7014x over previous
//
#include <hip/hip_runtime.h>
#include <math.h>

#define BLOCK 256
#define GRID 8192          // 4x wave-slot capacity -> smooth fill/drain
#define FBLOCK 1024
#define RELEASE_PROB 0.9f

// Pass 1: grid-stride float4 reduction; one partial per block into d_ws.
__global__ __launch_bounds__(BLOCK) void neuron_partial(
    const float4* __restrict__ x,
    const float4* __restrict__ w,
    const float4* __restrict__ f,
    const float4* __restrict__ u,
    float* __restrict__ partials,
    int n4)
{
    const int tid = blockIdx.x * BLOCK + threadIdx.x;
    const int stride = GRID * BLOCK;

    float acc = 0.0f;
    for (int i = tid; i < n4; i += stride) {
        const float4 xv = x[i];
        const float4 wv = w[i];
        const float4 fv = f[i];
        const float4 uv = u[i];
        acc += (uv.x < RELEASE_PROB) ? wv.x * fv.x * xv.x : 0.0f;
        acc += (uv.y < RELEASE_PROB) ? wv.y * fv.y * xv.y : 0.0f;
        acc += (uv.z < RELEASE_PROB) ? wv.z * fv.z * xv.z : 0.0f;
        acc += (uv.w < RELEASE_PROB) ? wv.w * fv.w * xv.w : 0.0f;
    }

    #pragma unroll
    for (int off = 32; off > 0; off >>= 1)
        acc += __shfl_down(acc, off, 64);

    __shared__ float sm[BLOCK / 64];
    const int lane = threadIdx.x & 63;
    const int wave = threadIdx.x >> 6;
    if (lane == 0) sm[wave] = acc;
    __syncthreads();

    if (threadIdx.x == 0) {
        float s = 0.0f;
        #pragma unroll
        for (int k = 0; k < BLOCK / 64; ++k) s += sm[k];
        partials[blockIdx.x] = s;
    }
}

// Pass 2: one block reduces GRID partials, applies threshold + tanh.
__global__ __launch_bounds__(FBLOCK) void neuron_final(
    const float* __restrict__ partials,
    const float* __restrict__ threshold,
    float* __restrict__ out)
{
    float acc = 0.0f;
    for (int i = threadIdx.x; i < GRID; i += FBLOCK)
        acc += partials[i];

    #pragma unroll
    for (int off = 32; off > 0; off >>= 1)
        acc += __shfl_down(acc, off, 64);

    __shared__ float sm[FBLOCK / 64];
    const int lane = threadIdx.x & 63;
    const int wave = threadIdx.x >> 6;
    if (lane == 0) sm[wave] = acc;
    __syncthreads();

    if (threadIdx.x == 0) {
        float total = 0.0f;
        #pragma unroll
        for (int k = 0; k < FBLOCK / 64; ++k) total += sm[k];
        out[0] = (total > threshold[0]) ? tanhf(total) : 0.0f;
    }
}

extern "C" void kernel_launch(void* const* d_in, const int* in_sizes, int n_in,
                              void* d_out, int out_size, void* d_ws, size_t ws_size,
                              hipStream_t stream)
{
    const float* x   = (const float*)d_in[0];
    const float* w   = (const float*)d_in[1];
    const float* f   = (const float*)d_in[2];
    const float* u   = (const float*)d_in[3];
    const float* thr = (const float*)d_in[4];

    float* out = (float*)d_out;
    float* partials = (float*)d_ws;   // GRID floats = 32 KB scratch

    const int n  = in_sizes[0];       // 16777216
    const int n4 = n / 4;

    neuron_partial<<<GRID, BLOCK, 0, stream>>>(
        (const float4*)x, (const float4*)w, (const float4*)f, (const float4*)u,
        partials, n4);

    neuron_final<<<1, FBLOCK, 0, stream>>>(partials, thr, out);
}